// Round 11
// baseline (367.505 us; speedup 1.0000x reference)
//
#include <hip/hip_runtime.h>
#include <hip/hip_bf16.h>

#define C 128
#define RBFD 20
#define NATOMS 50000
#define SCAN_CHUNK 1024
#define SLAB 64           // edges per gather wave; 800000 % 64 == 0

// ---------------------------------------------------------------------------
// Kernel 1: setup — transpose W1, W2 into [in][out], zero histogram counters,
// zero the accumulator (needed: boundary atomics + atoms with zero edges).
// ---------------------------------------------------------------------------
__global__ __launch_bounds__(256) void setup_kernel(
    const float* __restrict__ W1, const float* __restrict__ W2,
    float* __restrict__ W1T, float* __restrict__ W2T,
    int* __restrict__ count, float4* __restrict__ acc4,
    int n, int acc_quads)
{
    const int t = blockIdx.x * blockDim.x + threadIdx.x;
    const int stride = gridDim.x * blockDim.x;
    if (t < C * C) {
        int k = t / C;   // in-channel
        int c = t % C;   // out-channel
        W1T[t] = W1[c * C + k];
        W2T[t] = W2[c * C + k];
    }
    for (int i = t; i < n; i += stride) count[i] = 0;
    const float4 z = make_float4(0.f, 0.f, 0.f, 0.f);
    for (int i = t; i < acc_quads; i += stride) acc4[i] = z;
}

// ---------------------------------------------------------------------------
// CSR construction: histogram -> hierarchical exclusive scan -> perm fill
// ---------------------------------------------------------------------------
__global__ __launch_bounds__(256) void histogram_kernel(
    const int* __restrict__ idx, int* __restrict__ count, int E)
{
    int e = blockIdx.x * blockDim.x + threadIdx.x;
    if (e < E) atomicAdd(&count[idx[e]], 1);
}

__global__ __launch_bounds__(256) void scan_partials_kernel(
    const int* __restrict__ count, int* __restrict__ partial, int n)
{
    __shared__ int sm[256];
    const int start = blockIdx.x * SCAN_CHUNK;
    int s = 0;
    for (int i = threadIdx.x; i < SCAN_CHUNK; i += 256) {
        int g = start + i;
        if (g < n) s += count[g];
    }
    sm[threadIdx.x] = s;
    __syncthreads();
    for (int off = 128; off > 0; off >>= 1) {
        if (threadIdx.x < off) sm[threadIdx.x] += sm[threadIdx.x + off];
        __syncthreads();
    }
    if (threadIdx.x == 0) partial[blockIdx.x] = sm[0];
}

__global__ void scan_chunkbase_kernel(int* __restrict__ partial,
                                      int* __restrict__ base,
                                      int nchunks, int n)
{
    if (threadIdx.x == 0 && blockIdx.x == 0) {
        int run = 0;
        for (int k = 0; k < nchunks; ++k) {
            int t = partial[k];
            partial[k] = run;
            run += t;
        }
        base[n] = run;
    }
}

__global__ __launch_bounds__(1024) void scan_apply_kernel(
    const int* __restrict__ count, const int* __restrict__ chunk_base,
    int* __restrict__ base, int* __restrict__ cursor, int n)
{
    __shared__ int sm[SCAN_CHUNK];
    const int t = threadIdx.x;
    const int i = blockIdx.x * SCAN_CHUNK + t;
    int v = (i < n) ? count[i] : 0;
    sm[t] = v;
    __syncthreads();
    for (int off = 1; off < SCAN_CHUNK; off <<= 1) {
        int tmp = (t >= off) ? sm[t - off] : 0;
        __syncthreads();
        sm[t] += tmp;
        __syncthreads();
    }
    if (i < n) {
        int excl = sm[t] - v + chunk_base[blockIdx.x];
        base[i] = excl;
        cursor[i] = excl;
    }
}

// also records the owner atom of each perm slot (sequential-read later)
__global__ __launch_bounds__(256) void fill_perm_kernel(
    const int* __restrict__ idx, int* __restrict__ cursor,
    int* __restrict__ perm, int* __restrict__ own, int E)
{
    int e = blockIdx.x * blockDim.x + threadIdx.x;
    if (e < E) {
        int a = idx[e];
        int pos = atomicAdd(&cursor[a], 1);
        perm[pos] = e;
        own[pos] = a;
    }
}

// ---------------------------------------------------------------------------
// Gather kernel v8: single-wave blocks, zero barriers, triple pipeline.
//  * Block = 64 threads = ONE wave = 64 channels; grid = (E/64) slabs x 2
//    channel-halves.  Waves are fully independent -> no __syncthreads in the
//    loop, no cross-wave vmcnt drains; the HW scheduler free-runs 12 waves/CU.
//  * x stream: depth-8 rotating register pipeline (xp/er, compile-time
//    indices after full unroll).  rbf stream: depth-2 named R5 structs
//    (L2-resident rows).  own/env: one ds_read_b64 broadcast at consume.
//  * sched_barrier(0) after each issue cluster pins loads above the FMAs.
//  * Segmented flush-on-owner-change; atomics only at wave-range boundaries.
//    Channel-halves write disjoint columns -> no races between halves.
// ---------------------------------------------------------------------------
struct R5 { float4 a, b, c, d, e; };

__device__ __forceinline__ R5 load_rbf5(const float* __restrict__ rbf, int eidx) {
    const float4* q = reinterpret_cast<const float4*>(rbf + (size_t)eidx * RBFD);
    R5 r;
    r.a = q[0]; r.b = q[1]; r.c = q[2]; r.d = q[3]; r.e = q[4];
    return r;
}

__device__ __forceinline__ float dot20(const R5& p, const float* __restrict__ w,
                                       float bias) {
    float f = bias;
    f = fmaf(p.a.x, w[0],  f); f = fmaf(p.a.y, w[1],  f);
    f = fmaf(p.a.z, w[2],  f); f = fmaf(p.a.w, w[3],  f);
    f = fmaf(p.b.x, w[4],  f); f = fmaf(p.b.y, w[5],  f);
    f = fmaf(p.b.z, w[6],  f); f = fmaf(p.b.w, w[7],  f);
    f = fmaf(p.c.x, w[8],  f); f = fmaf(p.c.y, w[9],  f);
    f = fmaf(p.c.z, w[10], f); f = fmaf(p.c.w, w[11], f);
    f = fmaf(p.d.x, w[12], f); f = fmaf(p.d.y, w[13], f);
    f = fmaf(p.d.z, w[14], f); f = fmaf(p.d.w, w[15], f);
    f = fmaf(p.e.x, w[16], f); f = fmaf(p.e.y, w[17], f);
    f = fmaf(p.e.z, w[18], f); f = fmaf(p.e.w, w[19], f);
    return f;
}

__global__ __launch_bounds__(64, 3) void gather_kernel(
    const float* __restrict__ x,       // [E][C]
    const float* __restrict__ rbf,     // [E][RBFD]
    const float* __restrict__ env,     // [E]
    const int*   __restrict__ perm,    // [E]
    const int*   __restrict__ own,     // [E]
    const float* __restrict__ Wrbf,    // [C][RBFD]
    const float* __restrict__ brbf,    // [C]
    float* __restrict__ acc)           // [N][C] (pre-zeroed)
{
    __shared__ int  e_s[SLAB];
    __shared__ int2 oe_s[SLAB];        // .x = owner atom, .y = env bits

    const int tid  = threadIdx.x;      // 0..63
    const int bid  = blockIdx.x;
    const int slab = bid >> 1;
    const int ch   = ((bid & 1) << 6) | tid;   // channel 0..127
    const int p0   = slab << 6;

    {
        const int e = perm[p0 + tid];
        e_s[tid]  = e;
        oe_s[tid] = make_int2(own[p0 + tid], __float_as_int(env[e]));
    }

    float w[RBFD];
#pragma unroll
    for (int r = 0; r < RBFD; ++r) w[r] = Wrbf[ch * RBFD + r];
    const float bias = brbf[ch];

    __syncthreads();   // one wave: effectively just a waitcnt; once per block

    const int first_own = oe_s[0].x;
    int   cur_own = first_own;
    float sum = 0.0f;

#define FLUSH()                                                                \
    do {                                                                       \
        if (cur_own == first_own)                                              \
            unsafeAtomicAdd(&acc[(size_t)cur_own * C + ch], sum);              \
        else acc[(size_t)cur_own * C + ch] = sum;                              \
    } while (0)

    // ---- prologue: x pipeline depth 8, rbf pipeline depth 2 ----
    int   er[8];
    float xp[8];
#pragma unroll
    for (int i = 0; i < 8; ++i) {
        er[i] = e_s[i];
        xp[i] = x[((size_t)er[i] << 7) + ch];
    }
    R5 Pa = load_rbf5(rbf, er[0]);
    R5 Pb = load_rbf5(rbf, er[1]);
    __builtin_amdgcn_sched_barrier(0);

#pragma unroll
    for (int j = 0; j < SLAB; j += 2) {
        // ---- issue clusters: rbf for edges j+2,j+3; x for edges j+8,j+9 ----
        R5 Na, Nb;
        if (j + 2 < SLAB) {
            Na = load_rbf5(rbf, er[(j + 2) & 7]);
            Nb = load_rbf5(rbf, er[(j + 3) & 7]);
        }
        int en0 = 0, en1 = 0;
        float xn0 = 0.0f, xn1 = 0.0f;
        if (j + 8 < SLAB) { en0 = e_s[j + 8]; xn0 = x[((size_t)en0 << 7) + ch]; }
        if (j + 9 < SLAB) { en1 = e_s[j + 9]; xn1 = x[((size_t)en1 << 7) + ch]; }
        __builtin_amdgcn_sched_barrier(0);

        // ---- consume edges j, j+1 ----
        const int2 m0 = oe_s[j];
        const int2 m1 = oe_s[j + 1];
        const float f0 = dot20(Pa, w, bias);
        const float f1 = dot20(Pb, w, bias);
        const float v0 = f0 * __int_as_float(m0.y) * xp[j & 7];
        const float v1 = f1 * __int_as_float(m1.y) * xp[(j + 1) & 7];

        if (m0.x != cur_own) { FLUSH(); sum = 0.0f; cur_own = m0.x; }
        sum += v0;
        if (m1.x != cur_own) { FLUSH(); sum = 0.0f; cur_own = m1.x; }
        sum += v1;

        // ---- rotate pipelines (compile-time indices after full unroll) ----
        if (j + 8 < SLAB) { er[j & 7] = en0; xp[j & 7] = xn0; }
        if (j + 9 < SLAB) { er[(j + 1) & 7] = en1; xp[(j + 1) & 7] = xn1; }
        Pa = Na; Pb = Nb;
    }
    // final flush: cur_own may span into the next slab -> atomic
    unsafeAtomicAdd(&acc[(size_t)cur_own * C + ch], sum);
#undef FLUSH
}

// ---------------------------------------------------------------------------
// Fused MLP head (unchanged).
// ---------------------------------------------------------------------------
__device__ __forceinline__ float silu_f(float v) {
    return v * (1.0f / (1.0f + __expf(-v)));
}

__global__ __launch_bounds__(256) void mlp_head_kernel(
    const float* __restrict__ acc,   // [N][C]
    const float* __restrict__ W1T,   // [C][C]  (k-major)
    const float* __restrict__ b1,    // [C]
    const float* __restrict__ W2T,   // [C][C]
    const float* __restrict__ b2,    // [C]
    const float* __restrict__ W3,    // [1][C]
    const float* __restrict__ b3,    // [1]
    float* __restrict__ out,         // [N]
    int natoms)
{
    __shared__ float As[C][C + 1];

    const int tid = threadIdx.x;
    const int a0  = blockIdx.x * C;
    const int tc  = tid & 15;
    const int ta  = tid >> 4;
    const int abase = ta * 8;
    const int cbase = tc * 8;

    {
        const int sub = tid >> 7;
        const int k   = tid & 127;
        for (int pair = 0; pair < 64; ++pair) {
            const int al = pair * 2 + sub;
            const int a  = a0 + al;
            float v = (a < natoms) ? acc[(size_t)a * C + k] : 0.0f;
            As[k][al] = v;
        }
    }
    __syncthreads();

    float r[8][8];

    // layer 1
#pragma unroll
    for (int i = 0; i < 8; ++i)
#pragma unroll
        for (int j = 0; j < 8; ++j) r[i][j] = 0.0f;

#pragma unroll 2
    for (int k = 0; k < C; ++k) {
        float4 bq0 = *reinterpret_cast<const float4*>(W1T + k * C + cbase);
        float4 bq1 = *reinterpret_cast<const float4*>(W1T + k * C + cbase + 4);
        float bv[8] = {bq0.x, bq0.y, bq0.z, bq0.w, bq1.x, bq1.y, bq1.z, bq1.w};
        float av[8];
#pragma unroll
        for (int i = 0; i < 8; ++i) av[i] = As[k][abase + i];
#pragma unroll
        for (int i = 0; i < 8; ++i)
#pragma unroll
            for (int j = 0; j < 8; ++j) r[i][j] = fmaf(av[i], bv[j], r[i][j]);
    }

    __syncthreads();
    {
        float bb[8];
#pragma unroll
        for (int j = 0; j < 8; ++j) bb[j] = b1[cbase + j];
#pragma unroll
        for (int i = 0; i < 8; ++i)
#pragma unroll
            for (int j = 0; j < 8; ++j)
                As[cbase + j][abase + i] = silu_f(r[i][j] + bb[j]);
    }
    __syncthreads();

    // layer 2
#pragma unroll
    for (int i = 0; i < 8; ++i)
#pragma unroll
        for (int j = 0; j < 8; ++j) r[i][j] = 0.0f;

#pragma unroll 2
    for (int k = 0; k < C; ++k) {
        float4 bq0 = *reinterpret_cast<const float4*>(W2T + k * C + cbase);
        float4 bq1 = *reinterpret_cast<const float4*>(W2T + k * C + cbase + 4);
        float bv[8] = {bq0.x, bq0.y, bq0.z, bq0.w, bq1.x, bq1.y, bq1.z, bq1.w};
        float av[8];
#pragma unroll
        for (int i = 0; i < 8; ++i) av[i] = As[k][abase + i];
#pragma unroll
        for (int i = 0; i < 8; ++i)
#pragma unroll
            for (int j = 0; j < 8; ++j) r[i][j] = fmaf(av[i], bv[j], r[i][j]);
    }

    __syncthreads();

    // final: silu(.. + b2) . W3
    {
        float bb[8], w3v[8];
#pragma unroll
        for (int j = 0; j < 8; ++j) bb[j] = b2[cbase + j];
        float4 wq0 = *reinterpret_cast<const float4*>(W3 + cbase);
        float4 wq1 = *reinterpret_cast<const float4*>(W3 + cbase + 4);
        w3v[0]=wq0.x; w3v[1]=wq0.y; w3v[2]=wq0.z; w3v[3]=wq0.w;
        w3v[4]=wq1.x; w3v[5]=wq1.y; w3v[6]=wq1.z; w3v[7]=wq1.w;

#pragma unroll
        for (int i = 0; i < 8; ++i) {
            float p = 0.0f;
#pragma unroll
            for (int j = 0; j < 8; ++j)
                p = fmaf(silu_f(r[i][j] + bb[j]), w3v[j], p);
            As[abase + i][tc] = p;
        }
    }
    __syncthreads();

    if (tid < C) {
        const int a = a0 + tid;
        if (a < natoms) {
            float s = 0.0f;
#pragma unroll
            for (int t = 0; t < 16; ++t) s += As[tid][t];
            out[a] = s + b3[0];
        }
    }
}

// ---------------------------------------------------------------------------
extern "C" void kernel_launch(void* const* d_in, const int* in_sizes, int n_in,
                              void* d_out, int out_size, void* d_ws, size_t ws_size,
                              hipStream_t stream) {
    const float* x      = (const float*)d_in[0];
    const float* rbf    = (const float*)d_in[1];
    const float* env    = (const float*)d_in[2];
    const int*   idx    = (const int*)  d_in[3];
    const float* Wrbf   = (const float*)d_in[5];
    const float* brbf   = (const float*)d_in[6];
    const float* W1     = (const float*)d_in[7];
    const float* b1     = (const float*)d_in[8];
    const float* W2     = (const float*)d_in[9];
    const float* b2     = (const float*)d_in[10];
    const float* W3     = (const float*)d_in[11];
    const float* b3     = (const float*)d_in[12];
    float*       out    = (float*)d_out;

    const int E = in_sizes[0] / C;        // 800000
    const int N = NATOMS;                 // 50000
    const int nchunks = (N + SCAN_CHUNK - 1) / SCAN_CHUNK;   // 49

    // workspace layout
    float* acc     = (float*)d_ws;                    // N*C
    float* W1T     = acc + (size_t)N * C;             // C*C
    float* W2T     = W1T + C * C;                     // C*C
    int*   count   = (int*)(W2T + C * C);             // N
    int*   base    = count + N;                       // N+1
    int*   cursor  = base + (N + 1);                  // N
    int*   partial = cursor + N;                      // 64
    int*   perm    = partial + 64;                    // E
    int*   own     = perm + E;                        // E

    // setup: transpose weights + zero counters + zero acc
    setup_kernel<<<2048, 256, 0, stream>>>(W1, W2, W1T, W2T, count,
                                           (float4*)acc, N, (N * C) / 4);

    histogram_kernel<<<(E + 255) / 256, 256, 0, stream>>>(idx, count, E);
    scan_partials_kernel<<<nchunks, 256, 0, stream>>>(count, partial, N);
    scan_chunkbase_kernel<<<1, 64, 0, stream>>>(partial, base, nchunks, N);
    scan_apply_kernel<<<nchunks, SCAN_CHUNK, 0, stream>>>(count, partial, base, cursor, N);
    fill_perm_kernel<<<(E + 255) / 256, 256, 0, stream>>>(idx, cursor, perm, own, E);

    // gather: one 64-thread (single-wave) block per (64-edge, 64-channel) tile
    gather_kernel<<<(E / SLAB) * 2, 64, 0, stream>>>(x, rbf, env, perm, own,
                                                     Wrbf, brbf, acc);

    const int tiles = (N + C - 1) / C;
    mlp_head_kernel<<<tiles, 256, 0, stream>>>(acc, W1T, b1, W2T, b2, W3, b3, out, N);
}